// Round 24
// baseline (108.968 us; speedup 1.0000x reference)
//
#include <hip/hip_runtime.h>
#include <hip/hip_bf16.h>

typedef __attribute__((ext_vector_type(4))) float          fx4;
typedef __attribute__((ext_vector_type(8))) __bf16         bfx8;
typedef __attribute__((ext_vector_type(8))) unsigned short usx8;
typedef __attribute__((ext_vector_type(4))) unsigned short usx4;

#define TLEN 2048
#define ROWS 4096   /* B*T */
#define D    1024

__device__ __forceinline__ float bf2f(unsigned short u) {
    union { unsigned int i; float f; } v; v.i = ((unsigned int)u) << 16; return v.f;
}
__device__ __forceinline__ unsigned short f2bf(float f) {
    union { float f; unsigned int i; } v; v.f = f;
    unsigned int r = v.i + 0x7fffu + ((v.i >> 16) & 1u);
    return (unsigned short)(r >> 16);
}
__device__ __forceinline__ unsigned int cvtpk_bf16(float lo, float hi) {
    unsigned int r;
    asm("v_cvt_pk_bf16_f32 %0, %1, %2" : "=v"(r) : "v"(lo), "v"(hi));
    return r;
}
__device__ __forceinline__ void gload_lds16(const unsigned short* g, unsigned short* l) {
    __builtin_amdgcn_global_load_lds((const __attribute__((address_space(1))) void*)g,
                                     (__attribute__((address_space(3))) void*)l, 16, 0, 0);
}

// ---------------- Prep: LN (0..4095) + weight convert (4096..5119) + RoPE table (5120..5631) ----------------
__device__ __forceinline__ usx4 cvt4(fx4 a) {
    usx4 o;
    #pragma unroll
    for (int j = 0; j < 4; j++) o[j] = f2bf(a[j]);
    return o;
}
__global__ __launch_bounds__(256) void prep_kernel(const float* __restrict__ x,
                                                   const float* __restrict__ g,
                                                   const float* __restrict__ bta,
                                                   const float* __restrict__ wq, const float* __restrict__ wk,
                                                   const float* __restrict__ wv, const float* __restrict__ wo,
                                                   unsigned short* __restrict__ hout,
                                                   unsigned short* __restrict__ wqkv,
                                                   unsigned short* __restrict__ wob,
                                                   float* __restrict__ ropeTab) {
    const int tid = threadIdx.x;
    if (blockIdx.x >= 5120) {
        // RoPE table: tab[pi][t] = {cos, sin}(t * 10000^(-pi/32)); pi-major [32][2048]
        const int idx = (blockIdx.x - 5120) * 256 + tid;   // 131072 entries
        const int pi_ = idx >> 11, t = idx & 2047;
        float inv = __builtin_amdgcn_exp2f(-0.415241011861f * (float)pi_);
        float ang = (float)t * inv;
        ropeTab[idx * 2]     = cosf(ang);
        ropeTab[idx * 2 + 1] = sinf(ang);
        return;
    }
    if (blockIdx.x >= 4096) {
        const int i = (blockIdx.x - 4096) * 256 + tid;   // usx4 units, 262144 per matrix
        ((usx4*)wqkv)[i]          = cvt4(((const fx4*)wq)[i]);
        ((usx4*)wqkv)[262144 + i] = cvt4(((const fx4*)wk)[i]);
        ((usx4*)wqkv)[524288 + i] = cvt4(((const fx4*)wv)[i]);
        ((usx4*)wob)[i]           = cvt4(((const fx4*)wo)[i]);
        return;
    }
    const int row = blockIdx.x;
    fx4 v = ((const fx4*)(x + (size_t)row * D))[tid];
    float s  = v[0] + v[1] + v[2] + v[3];
    float s2 = v[0]*v[0] + v[1]*v[1] + v[2]*v[2] + v[3]*v[3];
    #pragma unroll
    for (int mk = 32; mk >= 1; mk >>= 1) { s += __shfl_xor(s, mk); s2 += __shfl_xor(s2, mk); }
    __shared__ float red[8];
    const int wave = tid >> 6, lane = tid & 63;
    if (lane == 0) { red[wave] = s; red[4 + wave] = s2; }
    __syncthreads();
    s  = red[0] + red[1] + red[2] + red[3];
    s2 = red[4] + red[5] + red[6] + red[7];
    float mu   = s * (1.0f / D);
    float var  = s2 * (1.0f / D) - mu * mu;
    float rstd = rsqrtf(var + 1e-5f);
    fx4 gv = ((const fx4*)g)[tid];
    fx4 bv = ((const fx4*)bta)[tid];
    usx4 o;
    #pragma unroll
    for (int j = 0; j < 4; j++) o[j] = f2bf((v[j] - mu) * rstd * gv[j] + bv[j]);
    ((usx4*)hout)[(size_t)row * 256 + tid] = o;
}

// ---------------- Merged QK + V^T GEMM: 256x256 block, 8 waves (128x64/wave) ----------------
// 192 blocks (1/CU), XCD-chunked remap. 4-PHASE COUNTED-VMCNT schedule (T3+T4):
// per K-tile, 4 C-quadrant phases; each phase {12 ds_read || 1 stage-unit issue ->
// barrier -> setprio MFMA x16}; iteration-top waits vmcnt(2) (kt's 8 loads done,
// unit-0 of kt+1 stays in flight) — never drains to 0 in steady state.
// Write-safety: buf b^1 staged during kt; its readers finished at kt-1's last
// barrier. Buf b re-staged only after kt's final barrier. Uniform barrier counts.
// ids 0..127: C[tok][2048 qk] = hbuf * wqk^T with FUSED RoPE (table), bf16.
// ids 128..191: Vt — C[d][tok] = wv * hbuf^T stored pre-permuted for attn PV.
__global__ __launch_bounds__(512) void qkvt_gemm(const unsigned short* __restrict__ hbuf,
                                                 const unsigned short* __restrict__ wqkv,
                                                 unsigned short* __restrict__ qkout,
                                                 unsigned short* __restrict__ vtout,
                                                 const float* __restrict__ ropeTab) {
    constexpr int K = 1024;
    __shared__ __align__(16) unsigned short As[2][256 * 64];
    __shared__ __align__(16) unsigned short Bs[2][256 * 64];
    const int tid = threadIdx.x, lane = tid & 63, wave = tid >> 6;
    const int fr = lane & 15, fq = lane >> 4;
    const int wr = wave >> 2, wc = wave & 3;

    // XCD-chunked bijective remap: 192 blocks = 8 XCDs x 24
    const int id = (blockIdx.x & 7) * 24 + (blockIdx.x >> 3);
    const bool isqk = id < 128;
    int bm, bn;
    const unsigned short *Ab, *Bb;
    if (isqk) {
        bm = id & 15; bn = id >> 4;                                   // 16 x 8
        Ab = hbuf + (size_t)(bm * 256) * K;
        Bb = wqkv + (size_t)(bn * 256) * K;
    } else {
        int j = id - 128; bm = j & 3; bn = j >> 2;                    // 4 x 16
        Ab = wqkv + (size_t)(2048 * 1024) + (size_t)(bm * 256) * K;   // wv
        Bb = hbuf + (size_t)(bn * 256) * K;
    }

    const int srow   = wave * 8 + (lane >> 3);          // rows 0..63 per issue; row&7 = lane>>3
    const int sc_dst = (lane & 7) * 8;
    const int sc_src = ((lane & 7) ^ (lane >> 3)) * 8;

    // stage-unit U: 0/1 = A half0/half1, 2/3 = B half0/half1 (2 gload_lds16 each)
    #define STAGE_UNIT(BUF, KT, U)                                                         \
        {                                                                                  \
            const unsigned short* _src = ((U) < 2) ? Ab : Bb;                              \
            unsigned short* _dst = ((U) < 2) ? &As[BUF][0] : &Bs[BUF][0];                  \
            const int _r0 = srow + (((U) & 1) ? 128 : 0);                                  \
            gload_lds16(_src + (size_t)_r0 * K + (KT) + sc_src, _dst + _r0 * 64 + sc_dst); \
            gload_lds16(_src + (size_t)(_r0 + 64) * K + (KT) + sc_src,                     \
                        _dst + (_r0 + 64) * 64 + sc_dst);                                  \
        }

    // quadrant (MH, NH): aF rows wr*128+MH*64+m*16+fr, bF rows wc*64+NH*32+n*16+fr
    #define PHASE_COMPUTE(B_, MH, NH)                                                      \
        {                                                                                  \
            bfx8 aF[2][4], bF[2][2];                                                       \
            _Pragma("unroll")                                                              \
            for (int s = 0; s < 2; s++) {                                                  \
                _Pragma("unroll")                                                          \
                for (int m = 0; m < 4; m++)                                                \
                    aF[s][m] = *(const bfx8*)&As[B_][(wr * 128 + (MH) * 64 + m * 16 + fr) * 64 + \
                                                    (((s * 4 + fq) ^ (fr & 7)) * 8)];      \
                _Pragma("unroll")                                                          \
                for (int n = 0; n < 2; n++)                                                \
                    bF[s][n] = *(const bfx8*)&Bs[B_][(wc * 64 + (NH) * 32 + n * 16 + fr) * 64 + \
                                                    (((s * 4 + fq) ^ (fr & 7)) * 8)];      \
            }                                                                              \
            __builtin_amdgcn_s_setprio(1);                                                 \
            _Pragma("unroll")                                                              \
            for (int s = 0; s < 2; s++)                                                    \
                _Pragma("unroll")                                                          \
                for (int m = 0; m < 4; m++)                                                \
                    _Pragma("unroll")                                                      \
                    for (int n = 0; n < 2; n++)                                            \
                        acc[(MH) * 4 + m][(NH) * 2 + n] = __builtin_amdgcn_mfma_f32_16x16x32_bf16( \
                            aF[s][m], bF[s][n], acc[(MH) * 4 + m][(NH) * 2 + n], 0, 0, 0); \
            __builtin_amdgcn_s_setprio(0);                                                 \
        }

    fx4 acc[8][4];
    #pragma unroll
    for (int m = 0; m < 8; m++)
        #pragma unroll
        for (int n = 0; n < 4; n++) acc[m][n] = (fx4)0.0f;

    // prologue: stage all 4 units of K-tile 0 into buf 0 (8 loads)
    STAGE_UNIT(0, 0, 0) STAGE_UNIT(0, 0, 1) STAGE_UNIT(0, 0, 2) STAGE_UNIT(0, 0, 3)

    #pragma unroll 2
    for (int kt = 0; kt < K; kt += 64) {
        const int b = (kt >> 6) & 1;
        const bool more = (kt + 64 < K);
        if (more) {
            STAGE_UNIT(b ^ 1, kt + 64, 0)
            asm volatile("s_waitcnt vmcnt(2)" ::: "memory");   // kt's 8 loads done; 2 in flight
        } else {
            asm volatile("s_waitcnt vmcnt(0)" ::: "memory");
        }
        __builtin_amdgcn_s_barrier();          // all waves' kt loads landed
        PHASE_COMPUTE(b, 0, 0)
        if (more) STAGE_UNIT(b ^ 1, kt + 64, 1)
        __builtin_amdgcn_s_barrier();
        PHASE_COMPUTE(b, 0, 1)
        if (more) STAGE_UNIT(b ^ 1, kt + 64, 2)
        __builtin_amdgcn_s_barrier();
        PHASE_COMPUTE(b, 1, 0)
        if (more) STAGE_UNIT(b ^ 1, kt + 64, 3)
        __builtin_amdgcn_s_barrier();
        PHASE_COMPUTE(b, 1, 1)
        __builtin_amdgcn_s_barrier();          // separates reads of buf b from its re-staging
    }
    #undef STAGE_UNIT
    #undef PHASE_COMPUTE

    const int row0 = bm * 256 + wr * 128 + fq * 4;
    const int col0 = bn * 256 + wc * 64 + fr;
    if (isqk) {
        const float QS = 0.125f * 1.44269504088896f;
        const bool isq = bn < 4;
        const float sgn = (fr & 1) ? 1.0f : -1.0f;
        #pragma unroll
        for (int m = 0; m < 8; m++) {
            const int rbase = row0 + m * 16;
            const int tb = rbase & (TLEN - 1);
            #pragma unroll
            for (int n = 0; n < 4; n++) {
                const float* tp = ropeTab + ((((n * 8 + (fr >> 1)) << 11) | tb) << 1);
                fx4 csA = *(const fx4*)tp;        // c0,s0,c1,s1
                fx4 csB = *(const fx4*)(tp + 4);  // c2,s2,c3,s3
                #pragma unroll
                for (int j = 0; j < 4; j++) {
                    float c  = (j < 2) ? csA[2 * j]     : csB[2 * (j - 2)];
                    float s_ = (j < 2) ? csA[2 * j + 1] : csB[2 * (j - 2) + 1];
                    float self = acc[m][n][j];
                    float other = __shfl_xor(self, 1);
                    float o = self * c + other * (sgn * s_);
                    if (isq) o *= QS;
                    qkout[(size_t)(rbase + j) * 2048 + col0 + n * 16] = f2bf(o);
                }
            }
        }
    } else {
        const int bb = bn >> 3;   // 256-token blocks: batch boundary every 8 bn
        // permuted within-64 column: t_w = n*16+fr  ->  (n>>1)*32+(fr>>2)*8+(n&1)*4+(fr&3)
        #pragma unroll
        for (int m = 0; m < 8; m++)
            #pragma unroll
            for (int n = 0; n < 4; n++) {
                const int t = (col0 + n * 16) & (TLEN - 1);
                const int tp = (t & ~63) | ((n >> 1) * 32 + ((fr >> 2)) * 8 + ((n & 1)) * 4 + (fr & 3));
                #pragma unroll
                for (int j = 0; j < 4; j++) {
                    const int d = row0 + m * 16 + j;
                    vtout[(((size_t)(bb * 16 + (d >> 6)) * 64) + (d & 63)) * TLEN + tp] = f2bf(acc[m][n][j]);
                }
            }
    }
}

// ---------------- Output GEMM: 128x64 tile, 512 blocks, BK=64 swizzled, f32 out ----------------
__global__ __launch_bounds__(256) void gemm_out64(const unsigned short* __restrict__ A,
                                                  const unsigned short* __restrict__ B,
                                                  float* __restrict__ C) {
    constexpr int K = 1024;
    __shared__ __align__(16) unsigned short As[128 * 64];
    __shared__ __align__(16) unsigned short Bs[64 * 64];
    const int tid = threadIdx.x, lane = tid & 63, wave = tid >> 6;
    const int fr = lane & 15, fq = lane >> 4;
    const int bm = blockIdx.x, bn = blockIdx.y;
    const int wr = wave >> 1, wc = wave & 1;

    const int srow   = wave * 8 + (lane >> 3);
    const int sc_dst = (lane & 7) * 8;
    const int sc_src = ((lane & 7) ^ (lane >> 3)) * 8;
    const unsigned short* Ab = A + (size_t)(bm * 128) * K;
    const unsigned short* Bb = B + (size_t)(bn * 64) * K;

    fx4 acc[4][2];
    #pragma unroll
    for (int m = 0; m < 4; m++)
        #pragma unroll
        for (int n = 0; n < 2; n++) acc[m][n] = (fx4)0.0f;

    for (int kt = 0; kt < K; kt += 64) {
        #pragma unroll
        for (int i = 0; i < 4; i++) {
            const int r = srow + 32 * i;
            gload_lds16(Ab + (size_t)r * K + kt + sc_src, &As[r * 64 + sc_dst]);
            if (i < 2)
                gload_lds16(Bb + (size_t)r * K + kt + sc_src, &Bs[r * 64 + sc_dst]);
        }
        __syncthreads();
        #pragma unroll
        for (int s = 0; s < 2; s++) {
            bfx8 aF[4], bF[2];
            #pragma unroll
            for (int m = 0; m < 4; m++)
                aF[m] = *(const bfx8*)&As[(wr * 64 + m * 16 + fr) * 64 + (((s * 4 + fq) ^ (fr & 7)) * 8)];
            #pragma unroll
            for (int n = 0; n < 2; n++)
                bF[n] = *(const bfx8*)&Bs[(wc * 32 + n * 16 + fr) * 64 + (((s * 4 + fq) ^ (fr & 7)) * 8)];
            #pragma unroll
            for (int m = 0; m < 4; m++)
                #pragma unroll
                for (int n = 0; n < 2; n++)
                    acc[m][n] = __builtin_amdgcn_mfma_f32_16x16x32_bf16(aF[m], bF[n], acc[m][n], 0, 0, 0);
        }
        __syncthreads();
    }

    const int row0 = bm * 128 + wr * 64 + fq * 4;
    const int col0 = bn * 64 + wc * 32 + fr;
    #pragma unroll
    for (int m = 0; m < 4; m++)
        #pragma unroll
        for (int n = 0; n < 2; n++)
            #pragma unroll
            for (int j = 0; j < 4; j++)
                C[(size_t)(row0 + m * 16 + j) * 1024 + col0 + n * 16] = acc[m][n][j];
}

// ---------------- Flash attention (full, non-causal), bf16 MFMA ----------------
// 8 waves; wave owns 32 q-rows (groups g0,g1); block owns 256 q; grid 256
// (1 block/CU). KVBLK=128 (16 iterations). V^T stored as TWO [64][64] subtiles
// (proven conflict-free swizzle per subtile). UNNORMALIZED softmax (P=exp2(S);
// S bounded ~|7|). l via ones-row MFMA; V pre-permuted per 64-token block.
// SEPARATE PV loops per q-group (measured best vs merged-PV).
__global__ __launch_bounds__(512) void attn_kernel(const unsigned short* __restrict__ qk,
                                                   const unsigned short* __restrict__ vt,
                                                   unsigned short* __restrict__ ao) {
    // XCD swizzle: 256 blocks -> each XCD hosts 4 consecutive bh groups
    const int flat = blockIdx.x + (blockIdx.y << 3);
    const int sid  = (flat & 7) * 32 + (flat >> 3);
    const int qt = sid & 7, bh = sid >> 3;
    const int b = bh >> 4, hh = bh & 15;
    const int tid = threadIdx.x, lane = tid & 63, wave = tid >> 6;
    const int fr = lane & 15, fq = lane >> 4;

    __shared__ __align__(16) unsigned short sK[2][128 * 64];      // swizzled K tile [kv][d]
    __shared__ __align__(16) unsigned short sVt[2][2 * 64 * 64];  // 2 subtiles [d][t'64]

    const size_t rs = 2048;
    const unsigned short* qb  = qk + (size_t)b * TLEN * rs + hh * 64;
    const unsigned short* kb  = qb + 1024;
    const unsigned short* vtb = vt + (size_t)bh * (64 * TLEN);

    bfx8 qF[2][2];
    #pragma unroll
    for (int g = 0; g < 2; g++) {
        int qrow = qt * 256 + wave * 32 + g * 16 + fr;
        const unsigned short* qp = qb + (size_t)qrow * rs + fq * 8;
        qF[g][0] = *(const bfx8*)qp;
        qF[g][1] = *(const bfx8*)(qp + 32);
    }
    union { unsigned short us[8]; bfx8 bf; } ones_u;
    #pragma unroll
    for (int i = 0; i < 8; i++) ones_u.us[i] = 0x3F80;   // bf16 1.0

    // staging: per wave 2 K row-groups + 2 V row-groups (8 rows each)
    const int srow = lane >> 3;
    const int scol = ((lane & 7) ^ srow) * 8;

    #define STAGE_ATTN(BUF, KT)                                                          \
        {                                                                                \
            _Pragma("unroll")                                                            \
            for (int i = 0; i < 2; i++) {                                                \
                const int rg = wave * 2 + i;                                             \
                gload_lds16(kb + (size_t)((KT) + rg * 8 + srow) * rs + scol,             \
                            &sK[BUF][rg * 512 + lane * 8]);                              \
                const int sub = rg >> 3, drow = (rg & 7) * 8 + srow;                     \
                gload_lds16(vtb + (size_t)drow * TLEN + (KT) + sub * 64 + scol,          \
                            &sVt[BUF][rg * 512 + lane * 8]);                             \
            }                                                                            \
        }

    // ---- prologue: stage tile 0 into buf 0
    STAGE_ATTN(0, 0)

    fx4 oacc[2][4];
    fx4 oextra[2] = {(fx4)0.0f, (fx4)0.0f};
    #pragma unroll
    for (int g = 0; g < 2; g++)
        #pragma unroll
        for (int db = 0; db < 4; db++) oacc[g][db] = (fx4)0.0f;

    #pragma unroll 2
    for (int t = 0; t < 16; ++t) {
        const int buf = t & 1;
        __syncthreads();   // staging of buf drained; prior reads of buf^1 done

        if (t + 1 < 16) STAGE_ATTN(buf ^ 1, (t + 1) * 128)

        // ---- QK^T swapped: s0/s1[n][j] = S[kv = n*16+fq*4+j][q = fr] per group
        fx4 s0[8], s1[8];
        #pragma unroll
        for (int n = 0; n < 8; n++) { s0[n] = (fx4)0.0f; s1[n] = (fx4)0.0f; }
        __builtin_amdgcn_s_setprio(1);
        #pragma unroll
        for (int s = 0; s < 2; s++)
            #pragma unroll
            for (int n = 0; n < 8; n++) {
                bfx8 kF = *(const bfx8*)&sK[buf][(n * 16 + fr) * 64 + (((s * 4 + fq) ^ (fr & 7)) * 8)];
                s0[n] = __builtin_amdgcn_mfma_f32_16x16x32_bf16(kF, qF[0][s], s0[n], 0, 0, 0);
                s1[n] = __builtin_amdgcn_mfma_f32_16x16x32_bf16(kF, qF[1][s], s1[n], 0, 0, 0);
            }
        __builtin_amdgcn_s_setprio(0);

        // ---- unnormalized P = exp2(S), group 0
        unsigned int u0[8][2], u1[8][2];
        #pragma unroll
        for (int n = 0; n < 8; n++) {
            u0[n][0] = cvtpk_bf16(__builtin_amdgcn_exp2f(s0[n][0]), __builtin_amdgcn_exp2f(s0[n][1]));
            u0[n][1] = cvtpk_bf16(__builtin_amdgcn_exp2f(s0[n][2]), __builtin_amdgcn_exp2f(s0[n][3]));
        }

        // ---- PV g0 — exp2/cvtpk of g1 below overlaps on VALU/TRANS
        __builtin_amdgcn_s_setprio(1);
        #pragma unroll
        for (int sp = 0; sp < 4; sp++) {
            union { unsigned int ui[4]; bfx8 bf; } cv;
            cv.ui[0] = u0[2 * sp][0];     cv.ui[1] = u0[2 * sp][1];
            cv.ui[2] = u0[2 * sp + 1][0]; cv.ui[3] = u0[2 * sp + 1][1];
            #pragma unroll
            for (int db = 0; db < 4; db++) {
                bfx8 vF = *(const bfx8*)&sVt[buf][(sp >> 1) * 4096 + (db * 16 + fr) * 64 +
                                                 ((((sp & 1) * 4 + fq) ^ (fr & 7)) * 8)];
                oacc[0][db] = __builtin_amdgcn_mfma_f32_16x16x32_bf16(vF, cv.bf, oacc[0][db], 0, 0, 0);
            }
            oextra[0] = __builtin_amdgcn_mfma_f32_16x16x32_bf16(ones_u.bf, cv.bf, oextra[0], 0, 0, 0);
        }
        __builtin_amdgcn_s_setprio(0);

        #pragma unroll
        for (int n = 0; n < 8; n++) {
            u1[n][0] = cvtpk_bf16(__builtin_amdgcn_exp2f(s1[n][0]), __builtin_amdgcn_exp2f(s1[n][1]));
            u1[n][1] = cvtpk_bf16(__builtin_amdgcn_exp2f(s1[n][2]), __builtin_amdgcn_exp2f(s1[n][3]));
        }

        // ---- PV g1
        __builtin_amdgcn_s_setprio(1);
        #pragma unroll
        for (int sp = 0; sp < 4; sp++) {
            union { unsigned int ui[4]; bfx8 bf; } cv;
            cv.ui[0] = u1[2 * sp][0];     cv.ui[1] = u1[2 * sp][1];
            cv.ui[2] = u1[2 * sp + 1][0]; cv.ui[3] = u1[2 * sp + 1][1];
            #pragma unroll
            for (int db = 0; db < 4; db++) {
                bfx8 vF = *(const bfx8*)&sVt[buf][(sp >> 1) * 4096 + (db * 16 + fr) * 64 +
                                                 ((((sp & 1) * 4 + fq) ^ (fr & 7)) * 8)];
                oacc[1][db] = __builtin_amdgcn_mfma_f32_16x16x32_bf16(vF, cv.bf, oacc[1][db], 0, 0, 0);
            }
            oextra[1] = __builtin_amdgcn_mfma_f32_16x16x32_bf16(ones_u.bf, cv.bf, oextra[1], 0, 0, 0);
        }
        __builtin_amdgcn_s_setprio(0);
    }
    #undef STAGE_ATTN

    // ---- epilogue (all oextra[g][j] rows identical per q-column fr)
    #pragma unroll
    for (int g = 0; g < 2; g++) {
        float invl = 1.0f / oextra[g][0];
        const int qrow = qt * 256 + wave * 32 + g * 16 + fr;
        unsigned short* aop = ao + (size_t)(b * TLEN + qrow) * 1024 + hh * 64 + fq * 4;
        #pragma unroll
        for (int db = 0; db < 4; db++) {
            usx4 o4;
            #pragma unroll
            for (int j = 0; j < 4; j++) o4[j] = f2bf(oacc[g][db][j] * invl);
            *(usx4*)(aop + db * 16) = o4;
        }
    }
}

extern "C" void kernel_launch(void* const* d_in, const int* in_sizes, int n_in,
                              void* d_out, int out_size, void* d_ws, size_t ws_size,
                              hipStream_t stream) {
    const float* x    = (const float*)d_in[0];
    const float* wq   = (const float*)d_in[1];
    const float* wk   = (const float*)d_in[2];
    const float* wv   = (const float*)d_in[3];
    const float* wo   = (const float*)d_in[4];
    const float* lng  = (const float*)d_in[5];
    const float* lnb  = (const float*)d_in[6];

    char* ws = (char*)d_ws;
    unsigned short* wob  = (unsigned short*)(ws);                // 2 MB
    unsigned short* wqkv = (unsigned short*)(ws + (2u  << 20));  // 6 MB (wq|wk|wv)
    unsigned short* hbuf = (unsigned short*)(ws + (8u  << 20));  // 8 MB
    unsigned short* qk   = (unsigned short*)(ws + (16u << 20));  // 16 MB (q|k, roped)
    unsigned short* vtb  = (unsigned short*)(ws + (32u << 20));  // 8 MB (V^T, permuted per 64)
    unsigned short* ao   = (unsigned short*)(ws + (8u  << 20));  // aliases hbuf
    float* ropeTab = (float*)d_out;   // 512 KB scratch in d_out; overwritten by gemm_out64

    prep_kernel<<<5632, 256, 0, stream>>>(x, lng, lnb, wq, wk, wv, wo, hbuf, wqkv, wob, ropeTab);
    qkvt_gemm<<<192, 512, 0, stream>>>(hbuf, wqkv, qk, vtb, ropeTab);
    attn_kernel<<<dim3(8, 32), 512, 0, stream>>>(qk, vtb, ao);
    gemm_out64<<<dim3(32, 16), 256, 0, stream>>>(ao, wob, (float*)d_out);
}

// Round 25
// 107.199 us; speedup vs baseline: 1.0165x; 1.0165x over previous
//
#include <hip/hip_runtime.h>
#include <hip/hip_bf16.h>

typedef __attribute__((ext_vector_type(4))) float          fx4;
typedef __attribute__((ext_vector_type(8))) __bf16         bfx8;
typedef __attribute__((ext_vector_type(8))) unsigned short usx8;
typedef __attribute__((ext_vector_type(4))) unsigned short usx4;

#define TLEN 2048
#define ROWS 4096   /* B*T */
#define D    1024

__device__ __forceinline__ float bf2f(unsigned short u) {
    union { unsigned int i; float f; } v; v.i = ((unsigned int)u) << 16; return v.f;
}
__device__ __forceinline__ unsigned short f2bf(float f) {
    union { float f; unsigned int i; } v; v.f = f;
    unsigned int r = v.i + 0x7fffu + ((v.i >> 16) & 1u);
    return (unsigned short)(r >> 16);
}
__device__ __forceinline__ unsigned int cvtpk_bf16(float lo, float hi) {
    unsigned int r;
    asm("v_cvt_pk_bf16_f32 %0, %1, %2" : "=v"(r) : "v"(lo), "v"(hi));
    return r;
}
__device__ __forceinline__ void gload_lds16(const unsigned short* g, unsigned short* l) {
    __builtin_amdgcn_global_load_lds((const __attribute__((address_space(1))) void*)g,
                                     (__attribute__((address_space(3))) void*)l, 16, 0, 0);
}

// ---------------- Prep: LN (0..4095) + weight convert (4096..5119) + RoPE table (5120..5631) ----------------
__device__ __forceinline__ usx4 cvt4(fx4 a) {
    usx4 o;
    #pragma unroll
    for (int j = 0; j < 4; j++) o[j] = f2bf(a[j]);
    return o;
}
__global__ __launch_bounds__(256) void prep_kernel(const float* __restrict__ x,
                                                   const float* __restrict__ g,
                                                   const float* __restrict__ bta,
                                                   const float* __restrict__ wq, const float* __restrict__ wk,
                                                   const float* __restrict__ wv, const float* __restrict__ wo,
                                                   unsigned short* __restrict__ hout,
                                                   unsigned short* __restrict__ wqkv,
                                                   unsigned short* __restrict__ wob,
                                                   float* __restrict__ ropeTab) {
    const int tid = threadIdx.x;
    if (blockIdx.x >= 5120) {
        // RoPE table: tab[pi][t] = {cos, sin}(t * 10000^(-pi/32)); pi-major [32][2048]
        const int idx = (blockIdx.x - 5120) * 256 + tid;   // 131072 entries
        const int pi_ = idx >> 11, t = idx & 2047;
        float inv = __builtin_amdgcn_exp2f(-0.415241011861f * (float)pi_);
        float ang = (float)t * inv;
        ropeTab[idx * 2]     = cosf(ang);
        ropeTab[idx * 2 + 1] = sinf(ang);
        return;
    }
    if (blockIdx.x >= 4096) {
        const int i = (blockIdx.x - 4096) * 256 + tid;   // usx4 units, 262144 per matrix
        ((usx4*)wqkv)[i]          = cvt4(((const fx4*)wq)[i]);
        ((usx4*)wqkv)[262144 + i] = cvt4(((const fx4*)wk)[i]);
        ((usx4*)wqkv)[524288 + i] = cvt4(((const fx4*)wv)[i]);
        ((usx4*)wob)[i]           = cvt4(((const fx4*)wo)[i]);
        return;
    }
    const int row = blockIdx.x;
    fx4 v = ((const fx4*)(x + (size_t)row * D))[tid];
    float s  = v[0] + v[1] + v[2] + v[3];
    float s2 = v[0]*v[0] + v[1]*v[1] + v[2]*v[2] + v[3]*v[3];
    #pragma unroll
    for (int mk = 32; mk >= 1; mk >>= 1) { s += __shfl_xor(s, mk); s2 += __shfl_xor(s2, mk); }
    __shared__ float red[8];
    const int wave = tid >> 6, lane = tid & 63;
    if (lane == 0) { red[wave] = s; red[4 + wave] = s2; }
    __syncthreads();
    s  = red[0] + red[1] + red[2] + red[3];
    s2 = red[4] + red[5] + red[6] + red[7];
    float mu   = s * (1.0f / D);
    float var  = s2 * (1.0f / D) - mu * mu;
    float rstd = rsqrtf(var + 1e-5f);
    fx4 gv = ((const fx4*)g)[tid];
    fx4 bv = ((const fx4*)bta)[tid];
    usx4 o;
    #pragma unroll
    for (int j = 0; j < 4; j++) o[j] = f2bf((v[j] - mu) * rstd * gv[j] + bv[j]);
    ((usx4*)hout)[(size_t)row * 256 + tid] = o;
}

// ---------------- Merged QK + V^T GEMM: 256x256 block, 8 waves (128x64/wave) ----------------
// 192 blocks (1/CU), XCD-chunked remap (bijective 192=8x24). A and B staged in
// LDS (dbuf, both-sides XOR swizzle), unroll-2 (compile-time buf index).
// ids 0..127: C[tok][2048 qk] = hbuf * wqk^T with FUSED RoPE (table), bf16.
// ids 128..191: Vt — C[d][tok] = wv * hbuf^T stored to Vt[(b*16+d>>6)*64+(d&63)][t']
//   with within-64-token permutation (kills attn's P cross-lane movement).
__global__ __launch_bounds__(512) void qkvt_gemm(const unsigned short* __restrict__ hbuf,
                                                 const unsigned short* __restrict__ wqkv,
                                                 unsigned short* __restrict__ qkout,
                                                 unsigned short* __restrict__ vtout,
                                                 const float* __restrict__ ropeTab) {
    constexpr int K = 1024;
    __shared__ __align__(16) unsigned short As[2][256 * 64];
    __shared__ __align__(16) unsigned short Bs[2][256 * 64];
    const int tid = threadIdx.x, lane = tid & 63, wave = tid >> 6;
    const int fr = lane & 15, fq = lane >> 4;
    const int wr = wave >> 2, wc = wave & 3;

    // XCD-chunked bijective remap: 192 blocks = 8 XCDs x 24
    const int id = (blockIdx.x & 7) * 24 + (blockIdx.x >> 3);
    const bool isqk = id < 128;
    int bm, bn;
    const unsigned short *Ab, *Bb;
    if (isqk) {
        bm = id & 15; bn = id >> 4;                                   // 16 x 8
        Ab = hbuf + (size_t)(bm * 256) * K;
        Bb = wqkv + (size_t)(bn * 256) * K;
    } else {
        int j = id - 128; bm = j & 3; bn = j >> 2;                    // 4 x 16
        Ab = wqkv + (size_t)(2048 * 1024) + (size_t)(bm * 256) * K;   // wv
        Bb = hbuf + (size_t)(bn * 256) * K;
    }

    const int srow   = wave * 8 + (lane >> 3);          // 0..63 (+64 per round); row&7 = lane>>3
    const int sc_dst = (lane & 7) * 8;
    const int sc_src = ((lane & 7) ^ (lane >> 3)) * 8;

    #define STAGE_Q(BUF, KT)                                                          \
        {                                                                             \
            _Pragma("unroll")                                                         \
            for (int i = 0; i < 4; i++) {                                             \
                const int r = srow + 64 * i;                                          \
                gload_lds16(Ab + (size_t)r * K + (KT) + sc_src, &As[BUF][r * 64 + sc_dst]); \
                gload_lds16(Bb + (size_t)r * K + (KT) + sc_src, &Bs[BUF][r * 64 + sc_dst]); \
            }                                                                         \
        }

    fx4 acc[8][4];
    #pragma unroll
    for (int m = 0; m < 8; m++)
        #pragma unroll
        for (int n = 0; n < 4; n++) acc[m][n] = (fx4)0.0f;

    STAGE_Q(0, 0)

    #pragma unroll 2
    for (int kt = 0; kt < K; kt += 64) {
        const int b = (kt >> 6) & 1;
        __syncthreads();                       // buf b staged; prior reads of b^1 done
        if (kt + 64 < K) STAGE_Q(b ^ 1, kt + 64)
        #pragma unroll
        for (int s = 0; s < 2; s++) {
            bfx8 aF[8], bF[4];
            #pragma unroll
            for (int m = 0; m < 8; m++)
                aF[m] = *(const bfx8*)&As[b][(wr * 128 + m * 16 + fr) * 64 + (((s * 4 + fq) ^ (fr & 7)) * 8)];
            #pragma unroll
            for (int n = 0; n < 4; n++)
                bF[n] = *(const bfx8*)&Bs[b][(wc * 64 + n * 16 + fr) * 64 + (((s * 4 + fq) ^ (fr & 7)) * 8)];
            #pragma unroll
            for (int m = 0; m < 8; m++)
                #pragma unroll
                for (int n = 0; n < 4; n++)
                    acc[m][n] = __builtin_amdgcn_mfma_f32_16x16x32_bf16(aF[m], bF[n], acc[m][n], 0, 0, 0);
        }
    }
    #undef STAGE_Q

    const int row0 = bm * 256 + wr * 128 + fq * 4;
    const int col0 = bn * 256 + wc * 64 + fr;
    if (isqk) {
        const float QS = 0.125f * 1.44269504088896f;
        const bool isq = bn < 4;
        const float sgn = (fr & 1) ? 1.0f : -1.0f;
        #pragma unroll
        for (int m = 0; m < 8; m++) {
            const int rbase = row0 + m * 16;
            const int tb = rbase & (TLEN - 1);
            #pragma unroll
            for (int n = 0; n < 4; n++) {
                const float* tp = ropeTab + ((((n * 8 + (fr >> 1)) << 11) | tb) << 1);
                fx4 csA = *(const fx4*)tp;        // c0,s0,c1,s1
                fx4 csB = *(const fx4*)(tp + 4);  // c2,s2,c3,s3
                #pragma unroll
                for (int j = 0; j < 4; j++) {
                    float c  = (j < 2) ? csA[2 * j]     : csB[2 * (j - 2)];
                    float s_ = (j < 2) ? csA[2 * j + 1] : csB[2 * (j - 2) + 1];
                    float self = acc[m][n][j];
                    float other = __shfl_xor(self, 1);
                    float o = self * c + other * (sgn * s_);
                    if (isq) o *= QS;
                    qkout[(size_t)(rbase + j) * 2048 + col0 + n * 16] = f2bf(o);
                }
            }
        }
    } else {
        const int bb = bn >> 3;   // 256-token blocks: batch boundary every 8 bn
        // permuted within-64 column: t_w = n*16+fr  ->  (n>>1)*32+(fr>>2)*8+(n&1)*4+(fr&3)
        #pragma unroll
        for (int m = 0; m < 8; m++)
            #pragma unroll
            for (int n = 0; n < 4; n++) {
                const int t = (col0 + n * 16) & (TLEN - 1);
                const int tp = (t & ~63) | ((n >> 1) * 32 + ((fr >> 2)) * 8 + ((n & 1)) * 4 + (fr & 3));
                #pragma unroll
                for (int j = 0; j < 4; j++) {
                    const int d = row0 + m * 16 + j;
                    vtout[(((size_t)(bb * 16 + (d >> 6)) * 64) + (d & 63)) * TLEN + tp] = f2bf(acc[m][n][j]);
                }
            }
    }
}

// ---------------- Output GEMM: 128x64 tile, 512 blocks, BK=64 swizzled, f32 out ----------------
__global__ __launch_bounds__(256) void gemm_out64(const unsigned short* __restrict__ A,
                                                  const unsigned short* __restrict__ B,
                                                  float* __restrict__ C) {
    constexpr int K = 1024;
    __shared__ __align__(16) unsigned short As[128 * 64];
    __shared__ __align__(16) unsigned short Bs[64 * 64];
    const int tid = threadIdx.x, lane = tid & 63, wave = tid >> 6;
    const int fr = lane & 15, fq = lane >> 4;
    const int bm = blockIdx.x, bn = blockIdx.y;
    const int wr = wave >> 1, wc = wave & 1;

    const int srow   = wave * 8 + (lane >> 3);
    const int sc_dst = (lane & 7) * 8;
    const int sc_src = ((lane & 7) ^ (lane >> 3)) * 8;
    const unsigned short* Ab = A + (size_t)(bm * 128) * K;
    const unsigned short* Bb = B + (size_t)(bn * 64) * K;

    fx4 acc[4][2];
    #pragma unroll
    for (int m = 0; m < 4; m++)
        #pragma unroll
        for (int n = 0; n < 2; n++) acc[m][n] = (fx4)0.0f;

    for (int kt = 0; kt < K; kt += 64) {
        #pragma unroll
        for (int i = 0; i < 4; i++) {
            const int r = srow + 32 * i;
            gload_lds16(Ab + (size_t)r * K + kt + sc_src, &As[r * 64 + sc_dst]);
            if (i < 2)
                gload_lds16(Bb + (size_t)r * K + kt + sc_src, &Bs[r * 64 + sc_dst]);
        }
        __syncthreads();
        #pragma unroll
        for (int s = 0; s < 2; s++) {
            bfx8 aF[4], bF[2];
            #pragma unroll
            for (int m = 0; m < 4; m++)
                aF[m] = *(const bfx8*)&As[(wr * 64 + m * 16 + fr) * 64 + (((s * 4 + fq) ^ (fr & 7)) * 8)];
            #pragma unroll
            for (int n = 0; n < 2; n++)
                bF[n] = *(const bfx8*)&Bs[(wc * 32 + n * 16 + fr) * 64 + (((s * 4 + fq) ^ (fr & 7)) * 8)];
            #pragma unroll
            for (int m = 0; m < 4; m++)
                #pragma unroll
                for (int n = 0; n < 2; n++)
                    acc[m][n] = __builtin_amdgcn_mfma_f32_16x16x32_bf16(aF[m], bF[n], acc[m][n], 0, 0, 0);
        }
        __syncthreads();
    }

    const int row0 = bm * 128 + wr * 64 + fq * 4;
    const int col0 = bn * 64 + wc * 32 + fr;
    #pragma unroll
    for (int m = 0; m < 4; m++)
        #pragma unroll
        for (int n = 0; n < 2; n++)
            #pragma unroll
            for (int j = 0; j < 4; j++)
                C[(size_t)(row0 + m * 16 + j) * 1024 + col0 + n * 16] = acc[m][n][j];
}

// ---------------- Flash attention (full, non-causal), bf16 MFMA ----------------
// 8 waves; wave owns 32 q-rows (groups g0,g1); block owns 256 q; grid 256
// (1 block/CU). KVBLK=128 (16 iterations). V^T stored as TWO [64][64] subtiles
// (proven conflict-free swizzle per subtile). UNNORMALIZED softmax (P=exp2(S);
// S bounded ~|7|). l via ones-row MFMA; V pre-permuted per 64-token block.
// SEPARATE PV loops per q-group (measured best vs merged-PV).
__global__ __launch_bounds__(512) void attn_kernel(const unsigned short* __restrict__ qk,
                                                   const unsigned short* __restrict__ vt,
                                                   unsigned short* __restrict__ ao) {
    // XCD swizzle: 256 blocks -> each XCD hosts 4 consecutive bh groups
    const int flat = blockIdx.x + (blockIdx.y << 3);
    const int sid  = (flat & 7) * 32 + (flat >> 3);
    const int qt = sid & 7, bh = sid >> 3;
    const int b = bh >> 4, hh = bh & 15;
    const int tid = threadIdx.x, lane = tid & 63, wave = tid >> 6;
    const int fr = lane & 15, fq = lane >> 4;

    __shared__ __align__(16) unsigned short sK[2][128 * 64];      // swizzled K tile [kv][d]
    __shared__ __align__(16) unsigned short sVt[2][2 * 64 * 64];  // 2 subtiles [d][t'64]

    const size_t rs = 2048;
    const unsigned short* qb  = qk + (size_t)b * TLEN * rs + hh * 64;
    const unsigned short* kb  = qb + 1024;
    const unsigned short* vtb = vt + (size_t)bh * (64 * TLEN);

    bfx8 qF[2][2];
    #pragma unroll
    for (int g = 0; g < 2; g++) {
        int qrow = qt * 256 + wave * 32 + g * 16 + fr;
        const unsigned short* qp = qb + (size_t)qrow * rs + fq * 8;
        qF[g][0] = *(const bfx8*)qp;
        qF[g][1] = *(const bfx8*)(qp + 32);
    }
    union { unsigned short us[8]; bfx8 bf; } ones_u;
    #pragma unroll
    for (int i = 0; i < 8; i++) ones_u.us[i] = 0x3F80;   // bf16 1.0

    // staging: per wave 2 K row-groups + 2 V row-groups (8 rows each)
    const int srow = lane >> 3;
    const int scol = ((lane & 7) ^ srow) * 8;

    #define STAGE_ATTN(BUF, KT)                                                          \
        {                                                                                \
            _Pragma("unroll")                                                            \
            for (int i = 0; i < 2; i++) {                                                \
                const int rg = wave * 2 + i;                                             \
                gload_lds16(kb + (size_t)((KT) + rg * 8 + srow) * rs + scol,             \
                            &sK[BUF][rg * 512 + lane * 8]);                              \
                const int sub = rg >> 3, drow = (rg & 7) * 8 + srow;                     \
                gload_lds16(vtb + (size_t)drow * TLEN + (KT) + sub * 64 + scol,          \
                            &sVt[BUF][rg * 512 + lane * 8]);                             \
            }                                                                            \
        }

    // ---- prologue: stage tile 0 into buf 0
    STAGE_ATTN(0, 0)

    fx4 oacc[2][4];
    fx4 oextra[2] = {(fx4)0.0f, (fx4)0.0f};
    #pragma unroll
    for (int g = 0; g < 2; g++)
        #pragma unroll
        for (int db = 0; db < 4; db++) oacc[g][db] = (fx4)0.0f;

    #pragma unroll 2
    for (int t = 0; t < 16; ++t) {
        const int buf = t & 1;
        __syncthreads();   // staging of buf drained; prior reads of buf^1 done

        if (t + 1 < 16) STAGE_ATTN(buf ^ 1, (t + 1) * 128)

        // ---- QK^T swapped: s0/s1[n][j] = S[kv = n*16+fq*4+j][q = fr] per group
        fx4 s0[8], s1[8];
        #pragma unroll
        for (int n = 0; n < 8; n++) { s0[n] = (fx4)0.0f; s1[n] = (fx4)0.0f; }
        __builtin_amdgcn_s_setprio(1);
        #pragma unroll
        for (int s = 0; s < 2; s++)
            #pragma unroll
            for (int n = 0; n < 8; n++) {
                bfx8 kF = *(const bfx8*)&sK[buf][(n * 16 + fr) * 64 + (((s * 4 + fq) ^ (fr & 7)) * 8)];
                s0[n] = __builtin_amdgcn_mfma_f32_16x16x32_bf16(kF, qF[0][s], s0[n], 0, 0, 0);
                s1[n] = __builtin_amdgcn_mfma_f32_16x16x32_bf16(kF, qF[1][s], s1[n], 0, 0, 0);
            }
        __builtin_amdgcn_s_setprio(0);

        // ---- unnormalized P = exp2(S), group 0
        unsigned int u0[8][2], u1[8][2];
        #pragma unroll
        for (int n = 0; n < 8; n++) {
            u0[n][0] = cvtpk_bf16(__builtin_amdgcn_exp2f(s0[n][0]), __builtin_amdgcn_exp2f(s0[n][1]));
            u0[n][1] = cvtpk_bf16(__builtin_amdgcn_exp2f(s0[n][2]), __builtin_amdgcn_exp2f(s0[n][3]));
        }

        // ---- PV g0 — exp2/cvtpk of g1 below overlaps on VALU/TRANS
        __builtin_amdgcn_s_setprio(1);
        #pragma unroll
        for (int sp = 0; sp < 4; sp++) {
            union { unsigned int ui[4]; bfx8 bf; } cv;
            cv.ui[0] = u0[2 * sp][0];     cv.ui[1] = u0[2 * sp][1];
            cv.ui[2] = u0[2 * sp + 1][0]; cv.ui[3] = u0[2 * sp + 1][1];
            #pragma unroll
            for (int db = 0; db < 4; db++) {
                bfx8 vF = *(const bfx8*)&sVt[buf][(sp >> 1) * 4096 + (db * 16 + fr) * 64 +
                                                 ((((sp & 1) * 4 + fq) ^ (fr & 7)) * 8)];
                oacc[0][db] = __builtin_amdgcn_mfma_f32_16x16x32_bf16(vF, cv.bf, oacc[0][db], 0, 0, 0);
            }
            oextra[0] = __builtin_amdgcn_mfma_f32_16x16x32_bf16(ones_u.bf, cv.bf, oextra[0], 0, 0, 0);
        }
        __builtin_amdgcn_s_setprio(0);

        #pragma unroll
        for (int n = 0; n < 8; n++) {
            u1[n][0] = cvtpk_bf16(__builtin_amdgcn_exp2f(s1[n][0]), __builtin_amdgcn_exp2f(s1[n][1]));
            u1[n][1] = cvtpk_bf16(__builtin_amdgcn_exp2f(s1[n][2]), __builtin_amdgcn_exp2f(s1[n][3]));
        }

        // ---- PV g1
        __builtin_amdgcn_s_setprio(1);
        #pragma unroll
        for (int sp = 0; sp < 4; sp++) {
            union { unsigned int ui[4]; bfx8 bf; } cv;
            cv.ui[0] = u1[2 * sp][0];     cv.ui[1] = u1[2 * sp][1];
            cv.ui[2] = u1[2 * sp + 1][0]; cv.ui[3] = u1[2 * sp + 1][1];
            #pragma unroll
            for (int db = 0; db < 4; db++) {
                bfx8 vF = *(const bfx8*)&sVt[buf][(sp >> 1) * 4096 + (db * 16 + fr) * 64 +
                                                 ((((sp & 1) * 4 + fq) ^ (fr & 7)) * 8)];
                oacc[1][db] = __builtin_amdgcn_mfma_f32_16x16x32_bf16(vF, cv.bf, oacc[1][db], 0, 0, 0);
            }
            oextra[1] = __builtin_amdgcn_mfma_f32_16x16x32_bf16(ones_u.bf, cv.bf, oextra[1], 0, 0, 0);
        }
        __builtin_amdgcn_s_setprio(0);
    }
    #undef STAGE_ATTN

    // ---- epilogue (all oextra[g][j] rows identical per q-column fr)
    #pragma unroll
    for (int g = 0; g < 2; g++) {
        float invl = 1.0f / oextra[g][0];
        const int qrow = qt * 256 + wave * 32 + g * 16 + fr;
        unsigned short* aop = ao + (size_t)(b * TLEN + qrow) * 1024 + hh * 64 + fq * 4;
        #pragma unroll
        for (int db = 0; db < 4; db++) {
            usx4 o4;
            #pragma unroll
            for (int j = 0; j < 4; j++) o4[j] = f2bf(oacc[g][db][j] * invl);
            *(usx4*)(aop + db * 16) = o4;
        }
    }
}

extern "C" void kernel_launch(void* const* d_in, const int* in_sizes, int n_in,
                              void* d_out, int out_size, void* d_ws, size_t ws_size,
                              hipStream_t stream) {
    const float* x    = (const float*)d_in[0];
    const float* wq   = (const float*)d_in[1];
    const float* wk   = (const float*)d_in[2];
    const float* wv   = (const float*)d_in[3];
    const float* wo   = (const float*)d_in[4];
    const float* lng  = (const float*)d_in[5];
    const float* lnb  = (const float*)d_in[6];

    char* ws = (char*)d_ws;
    unsigned short* wob  = (unsigned short*)(ws);                // 2 MB
    unsigned short* wqkv = (unsigned short*)(ws + (2u  << 20));  // 6 MB (wq|wk|wv)
    unsigned short* hbuf = (unsigned short*)(ws + (8u  << 20));  // 8 MB
    unsigned short* qk   = (unsigned short*)(ws + (16u << 20));  // 16 MB (q|k, roped)
    unsigned short* vtb  = (unsigned short*)(ws + (32u << 20));  // 8 MB (V^T, permuted per 64)
    unsigned short* ao   = (unsigned short*)(ws + (8u  << 20));  // aliases hbuf
    float* ropeTab = (float*)d_out;   // 512 KB scratch in d_out; overwritten by gemm_out64

    prep_kernel<<<5632, 256, 0, stream>>>(x, lng, lnb, wq, wk, wv, wo, hbuf, wqkv, wob, ropeTab);
    qkvt_gemm<<<192, 512, 0, stream>>>(hbuf, wqkv, qk, vtb, ropeTab);
    attn_kernel<<<dim3(8, 32), 512, 0, stream>>>(qk, vtb, ao);
    gemm_out64<<<dim3(32, 16), 256, 0, stream>>>(ao, wob, (float*)d_out);
}